// Round 6
// baseline (7086.543 us; speedup 1.0000x reference)
//
#include <hip/hip_runtime.h>
#include <hip/hip_bf16.h>
#include <stdint.h>

#define G_ 4
#define E_ 16
#define C_ 2048
#define H_ 512
#define F_ 2048

typedef __attribute__((ext_vector_type(8))) short bf16x8;
typedef __attribute__((ext_vector_type(4))) float f32x4;
typedef uint32_t u32_glb __attribute__((address_space(1)));
typedef uint32_t u32_lds __attribute__((address_space(3)));

__device__ __forceinline__ ushort f2bf(float f){
  uint u = __float_as_uint(f);
  return (ushort)((u + 0x7FFFu + ((u >> 16) & 1u)) >> 16);  // RNE
}

__device__ __forceinline__ bf16x8 pack8(f32x4 a, f32x4 b){
  union { bf16x8 v; uint u[4]; } p;
  p.u[0] = (uint)f2bf(a[0]) | ((uint)f2bf(a[1]) << 16);
  p.u[1] = (uint)f2bf(a[2]) | ((uint)f2bf(a[3]) << 16);
  p.u[2] = (uint)f2bf(b[0]) | ((uint)f2bf(b[1]) << 16);
  p.u[3] = (uint)f2bf(b[2]) | ((uint)f2bf(b[3]) << 16);
  return p.v;
}

__device__ __forceinline__ f32x4 gelu4(f32x4 v){
  f32x4 r;
  #pragma unroll
  for (int i = 0; i < 4; ++i){
    float t = v[i];
    r[i] = 0.5f * t * (1.0f + erff(t * 0.7071067811865475f));  // exact GELU
  }
  return r;
}

// transpose + fp32->bf16 convert: src [E][R][C] fp32 -> dst [E][C][R] bf16
__global__ void transpose_cvt(const float* __restrict__ src, ushort* __restrict__ dst,
                              int R, int C){
  __shared__ float tile[64][65];
  int c0 = blockIdx.x * 64, r0 = blockIdx.y * 64, e = blockIdx.z;
  int tx = threadIdx.x & 63, ty = threadIdx.x >> 6;   // 256 threads
  const float* s = src + (size_t)e * R * C;
  #pragma unroll
  for (int it = 0; it < 16; ++it){
    int row = ty + it * 4;
    tile[row][tx] = s[(size_t)(r0 + row) * C + (c0 + tx)];
  }
  __syncthreads();
  ushort* d = dst + (size_t)e * C * R;
  #pragma unroll
  for (int it = 0; it < 16; ++it){
    int row = ty + it * 4;
    d[(size_t)(c0 + row) * R + (r0 + tx)] = f2bf(tile[tx][row]);
  }
}

// ffn_fused4: BM=256, 1024 thr, 16 waves = 8 token-groups(32 tok) x 2 halves.
// GEMM1 f-split (wave: 32 tok x 16 f, W1-frag reused 2x), sA handoff,
// GEMM2 h-split (wave: 32 tok x 256 h, W2-frag reused 2x). All LDS XOR-swizzled.
__global__ __launch_bounds__(1024, 4) void ffn_fused4(
    const float* __restrict__ x,      // [G][E][C][H] fp32
    const float* __restrict__ b1,     // [E][F] fp32
    const float* __restrict__ b2,     // [E][H] fp32
    const ushort* __restrict__ w1t,   // [E][F][H] bf16
    const ushort* __restrict__ w2t,   // [E][H][F] bf16
    float* __restrict__ out){         // [G][E][C][H] fp32
  __shared__ ushort sW1[2][32 * 512];   // [f-row][h-k], swizzled key=(row&7)<<4
  __shared__ ushort sW2[2][512 * 32];   // [h-row][f-k], swizzled key=(h&6)<<3
  __shared__ ushort sA[256 * 32];       // [tok][f], swizzled key=(tok&6)<<3
  const int tid  = threadIdx.x;
  const int lane = tid & 63;
  const int wv   = tid >> 6;          // 0..15
  const int l15  = lane & 15;
  const int lg   = lane >> 4;         // 0..3
  const int tg   = wv >> 1;           // token-group 0..7 (32 tokens each)
  const int fh   = wv & 1;            // f-half (GEMM1) / h-half (GEMM2)

  // XCD-aware bijective swizzle: 512 blocks = 8 XCDs x 64 (2 experts/XCD)
  const int bid  = (blockIdx.x & 7) * 64 + (blockIdx.x >> 3);
  const int e    = bid >> 5;          // 32 blocks/expert
  const int mb   = bid & 31;
  const int n0   = mb * 256;
  const int g    = n0 >> 11;          // 256 | 2048: never crosses g
  const int c0   = n0 & (C_ - 1);

  // X fragments: wave's 32 tokens (2 tiles), lane row = l15, k = kk*32 + lg*8 + j
  bf16x8 xf[2][16];
  #pragma unroll
  for (int tt = 0; tt < 2; ++tt){
    const float* xrow = x + ((size_t)(g * E_ + e) * C_ + (c0 + tg * 32 + tt * 16 + l15)) * H_;
    #pragma unroll
    for (int kk = 0; kk < 16; ++kk){
      f32x4 fa = *(const f32x4*)(xrow + kk * 32 + lg * 8);
      f32x4 fb = *(const f32x4*)(xrow + kk * 32 + lg * 8 + 4);
      xf[tt][kk] = pack8(fa, fb);
    }
  }

  f32x4 acc2[2][16];                  // 128 regs: 32 tok x 256 h
  #pragma unroll
  for (int tt = 0; tt < 2; ++tt)
    #pragma unroll
    for (int ht = 0; ht < 16; ++ht)
      acc2[tt][ht] = (f32x4){0.f, 0.f, 0.f, 0.f};

  const ushort* w1e = w1t + (size_t)e * F_ * H_;
  const ushort* w2e = w2t + (size_t)e * H_ * F_;
  uint4 w2r[2];

  // W1: DMA 2 rows/wave, linear dest, pre-swizzled source (key=(r&7)<<4)
  #define STAGE_W1(F0, NB)                                                       \
    { _Pragma("unroll")                                                          \
      for (int it = 0; it < 2; ++it){                                            \
        int r = wv * 2 + it;                                                     \
        const ushort* gsrc = w1e + (size_t)((F0) + r) * H_                       \
                           + (((lane * 16) ^ ((r & 7) << 4)) >> 1);              \
        __builtin_amdgcn_global_load_lds((const u32_glb*)(uintptr_t)gsrc,        \
            (u32_lds*)(uintptr_t)(&sW1[(NB)][r * 512]), 16, 0, 0);               \
      } }
  // W2: reg-stage 2 uint4/thread (T14 split: issue early, write late)
  #define STAGE_W2_ISSUE(F0)                                                     \
    { _Pragma("unroll")                                                          \
      for (int it = 0; it < 2; ++it){                                            \
        int seg = it * 1024 + tid;                                               \
        w2r[it] = *(const uint4*)(w2e + (size_t)(seg >> 2) * F_ + (F0) + (seg & 3) * 8); \
      } }
  #define STAGE_W2_WRITE(NB)                                                     \
    { _Pragma("unroll")                                                          \
      for (int it = 0; it < 2; ++it){                                            \
        int seg = it * 1024 + tid;                                               \
        int h = seg >> 2, cq = seg & 3;                                          \
        *(uint4*)((char*)&sW2[(NB)][h * 32] + ((cq * 16) ^ ((h & 6) << 3))) = w2r[it]; \
      } }

  // prologue: stage chunk 0
  STAGE_W2_ISSUE(0)
  STAGE_W1(0, 0)
  STAGE_W2_WRITE(0)
  asm volatile("s_waitcnt vmcnt(0)" ::: "memory");
  __syncthreads();

  for (int ch = 0; ch < 64; ++ch){
    const int f0  = ch * 32;
    const int cur = ch & 1, nxt = cur ^ 1;
    if (ch < 63){                      // prefetch next chunk
      STAGE_W2_ISSUE(f0 + 32)
      STAGE_W1(f0 + 32, nxt)
    }

    // ---- GEMM1: wave's 16-f half x 32 tokens; W1-frag reused across 2 token-tiles
    f32x4 acc1[2];
    acc1[0] = (f32x4){0.f,0.f,0.f,0.f};
    acc1[1] = (f32x4){0.f,0.f,0.f,0.f};
    {
      const int r = fh * 16 + l15;     // sW1 row (f within chunk)
      const char* rbase = (const char*)&sW1[cur][r * 512];
      const int   sw    = (r & 7) << 4;
      #pragma unroll
      for (int kk = 0; kk < 16; ++kk){
        bf16x8 w1f = *(const bf16x8*)(rbase + (((kk * 64 + lg * 16) ^ sw)));
        acc1[0] = __builtin_amdgcn_mfma_f32_16x16x32_bf16(w1f, xf[0][kk], acc1[0], 0, 0, 0);
        acc1[1] = __builtin_amdgcn_mfma_f32_16x16x32_bf16(w1f, xf[1][kk], acc1[1], 0, 0, 0);
      }
    }

    // ---- bias + exact GELU -> sA[tok][f] (bf16, b64 writes, swizzled)
    {
      f32x4 bv = *(const f32x4*)(b1 + (size_t)e * F_ + f0 + fh * 16 + lg * 4);
      #pragma unroll
      for (int tt = 0; tt < 2; ++tt){
        f32x4 gv = gelu4(acc1[tt] + bv);   // D1: lane holds f=fh*16+lg*4+i, tok col=l15
        uint2 pk;
        pk.x = (uint)f2bf(gv[0]) | ((uint)f2bf(gv[1]) << 16);
        pk.y = (uint)f2bf(gv[2]) | ((uint)f2bf(gv[3]) << 16);
        int tok = tg * 32 + tt * 16 + l15;
        *(uint2*)((char*)&sA[tok * 32] + (((fh * 32 + lg * 8) ^ ((tok & 6) << 3)))) = pk;
      }
    }
    __syncthreads();                   // sA ready (all 32 f per token)

    // ---- GEMM2: wave's 256-h half x 32 tokens; W2-frag reused across 2 token-tiles
    {
      bf16x8 pa[2];
      #pragma unroll
      for (int tt = 0; tt < 2; ++tt){
        int tok = tg * 32 + tt * 16 + l15;
        pa[tt] = *(const bf16x8*)((char*)&sA[tok * 32] + ((lg * 16) ^ ((tok & 6) << 3)));
      }
      #pragma unroll
      for (int ht = 0; ht < 16; ++ht){
        int h = fh * 256 + ht * 16 + l15;
        bf16x8 w2f = *(const bf16x8*)((char*)&sW2[cur][h * 32] + ((lg * 16) ^ ((h & 6) << 3)));
        acc2[0][ht] = __builtin_amdgcn_mfma_f32_16x16x32_bf16(pa[0], w2f, acc2[0][ht], 0, 0, 0);
        acc2[1][ht] = __builtin_amdgcn_mfma_f32_16x16x32_bf16(pa[1], w2f, acc2[1][ht], 0, 0, 0);
      }
    }

    if (ch < 63) STAGE_W2_WRITE(nxt)
    asm volatile("s_waitcnt vmcnt(0)" ::: "memory");  // W1 DMA landed
    __syncthreads();                   // buffers swapped; sA reusable
  }

  // ---- epilogue: D2 row = token slot lg*4+i, col = h = fh*256+ht*16+l15
  const size_t obase = (size_t)(g * E_ + e) * C_ + (c0 + tg * 32 + lg * 4);
  #pragma unroll
  for (int ht = 0; ht < 16; ++ht){
    const int h  = fh * 256 + ht * 16 + l15;
    const float bb = b2[(size_t)e * H_ + h];
    #pragma unroll
    for (int tt = 0; tt < 2; ++tt){
      #pragma unroll
      for (int i = 0; i < 4; ++i)
        out[(obase + tt * 16 + i) * H_ + h] = acc2[tt][ht][i] + bb;
    }
  }
  #undef STAGE_W1
  #undef STAGE_W2_ISSUE
  #undef STAGE_W2_WRITE
}

extern "C" void kernel_launch(void* const* d_in, const int* in_sizes, int n_in,
                              void* d_out, int out_size, void* d_ws, size_t ws_size,
                              hipStream_t stream){
  const float *x = nullptr, *b1 = nullptr, *b2 = nullptr;
  const float* w12[2] = {nullptr, nullptr}; int nw = 0;
  for (int i = 0; i < n_in; ++i){
    long s = (long)in_sizes[i];
    if      (s == (long)G_ * E_ * C_ * H_) x = (const float*)d_in[i];
    else if (s == (long)E_ * H_ * F_) { if (nw < 2) w12[nw++] = (const float*)d_in[i]; }
    else if (s == (long)E_ * F_) b1 = (const float*)d_in[i];
    else if (s == (long)E_ * H_) b2 = (const float*)d_in[i];
  }
  const float* w1 = w12[0];
  const float* w2 = w12[1];
  if (!x || !w1 || !w2 || !b1 || !b2){
    x  = (const float*)d_in[0];
    w1 = (const float*)d_in[1];
    b1 = (const float*)d_in[2];
    w2 = (const float*)d_in[3];
    b2 = (const float*)d_in[4];
  }

  ushort* w1t = (ushort*)d_ws;                       // [E][F][H] bf16
  ushort* w2t = w1t + (size_t)E_ * F_ * H_;          // [E][H][F] bf16

  transpose_cvt<<<dim3(F_ / 64, H_ / 64, E_), dim3(256), 0, stream>>>(w1, w1t, H_, F_);
  transpose_cvt<<<dim3(H_ / 64, F_ / 64, E_), dim3(256), 0, stream>>>(w2, w2t, F_, H_);

  ffn_fused4<<<dim3(512), dim3(1024), 0, stream>>>(x, b1, b2, w1t, w2t, (float*)d_out);
}

// Round 7
// 1375.329 us; speedup vs baseline: 5.1526x; 5.1526x over previous
//
#include <hip/hip_runtime.h>
#include <hip/hip_bf16.h>
#include <stdint.h>

#define G_ 4
#define E_ 16
#define C_ 2048
#define H_ 512
#define F_ 2048

typedef __attribute__((ext_vector_type(8))) short bf16x8;
typedef __attribute__((ext_vector_type(4))) float f32x4;
typedef uint32_t u32_glb __attribute__((address_space(1)));
typedef uint32_t u32_lds __attribute__((address_space(3)));

__device__ __forceinline__ ushort f2bf(float f){
  uint u = __float_as_uint(f);
  return (ushort)((u + 0x7FFFu + ((u >> 16) & 1u)) >> 16);  // RNE
}

__device__ __forceinline__ bf16x8 pack8(f32x4 a, f32x4 b){
  union { bf16x8 v; uint u[4]; } p;
  p.u[0] = (uint)f2bf(a[0]) | ((uint)f2bf(a[1]) << 16);
  p.u[1] = (uint)f2bf(a[2]) | ((uint)f2bf(a[3]) << 16);
  p.u[2] = (uint)f2bf(b[0]) | ((uint)f2bf(b[1]) << 16);
  p.u[3] = (uint)f2bf(b[2]) | ((uint)f2bf(b[3]) << 16);
  return p.v;
}

__device__ __forceinline__ f32x4 gelu4(f32x4 v){
  f32x4 r;
  #pragma unroll
  for (int i = 0; i < 4; ++i){
    float t = v[i];
    r[i] = 0.5f * t * (1.0f + erff(t * 0.7071067811865475f));  // exact GELU
  }
  return r;
}

// transpose + fp32->bf16 convert: src [E][R][C] fp32 -> dst [E][C][R] bf16
__global__ void transpose_cvt(const float* __restrict__ src, ushort* __restrict__ dst,
                              int R, int C){
  __shared__ float tile[64][65];
  int c0 = blockIdx.x * 64, r0 = blockIdx.y * 64, e = blockIdx.z;
  int tx = threadIdx.x & 63, ty = threadIdx.x >> 6;   // 256 threads
  const float* s = src + (size_t)e * R * C;
  #pragma unroll
  for (int it = 0; it < 16; ++it){
    int row = ty + it * 4;
    tile[row][tx] = s[(size_t)(r0 + row) * C + (c0 + tx)];
  }
  __syncthreads();
  ushort* d = dst + (size_t)e * C * R;
  #pragma unroll
  for (int it = 0; it < 16; ++it){
    int row = ty + it * 4;
    d[(size_t)(c0 + row) * R + (r0 + tx)] = f2bf(tile[tx][row]);
  }
}

// ffn_fused5: BM=128, 512 thr, 8 waves = 4 token-groups(32 tok) x 2 K/h-halves.
// GEMM1 K-split (xf = 64 VGPR for 32 tokens), partial exchange via sEx;
// GELU on own f-half; pa exchange via sPa; GEMM2 full-K on own 256-h half.
// Per-chunk LDS bytes ~370 KB vs R5's ~510 KB; all patterns dense or 2-way.
__global__ __launch_bounds__(512, 2) void ffn_fused5(
    const float* __restrict__ x,      // [G][E][C][H] fp32
    const float* __restrict__ b1,     // [E][F] fp32
    const float* __restrict__ b2,     // [E][H] fp32
    const ushort* __restrict__ w1t,   // [E][F][H] bf16
    const ushort* __restrict__ w2t,   // [E][H][F] bf16
    float* __restrict__ out){         // [G][E][C][H] fp32
  __shared__ ushort sW1[2][32 * 512];     // 64 KB, linear, content XOR-swizzled
  __shared__ ushort sW2[2][512 * 32];     // 64 KB, [h](64B row), 8B-slot XOR (h&7)
  __shared__ f32x4  sEx[4][2][2][64];     // 16 KB [tg][tt][src_kh][lane]
  __shared__ uint2  sPa[4][2][2][64];     //  8 KB [tg][tt][src_kh][lane]
  const int tid  = threadIdx.x;
  const int lane = tid & 63;
  const int wv   = tid >> 6;          // 0..7
  const int l15  = lane & 15;
  const int lg   = lane >> 4;         // 0..3
  const int tg   = wv >> 1;           // token-group 0..3 (32 tokens)
  const int kh   = wv & 1;            // K-half (GEMM1) / h-half (GEMM2)

  // XCD-aware bijective swizzle: 1024 blocks = 8 XCDs x 128
  const int bid  = (blockIdx.x & 7) * 128 + (blockIdx.x >> 3);
  const int e    = bid >> 6;
  const int mb   = bid & 63;
  const int n0   = mb * 128;
  const int g    = n0 >> 11;
  const int c0   = n0 & (C_ - 1);

  // X fragments: 32 tokens, K-half only -> 64 VGPR. k = kh*256 + k8*32 + lg*8 + j
  bf16x8 xf[2][8];
  #pragma unroll
  for (int tt = 0; tt < 2; ++tt){
    const float* xr = x + ((size_t)(g * E_ + e) * C_ + (c0 + tg * 32 + tt * 16 + l15)) * H_
                    + kh * 256;
    #pragma unroll
    for (int k8 = 0; k8 < 8; ++k8){
      f32x4 fa = *(const f32x4*)(xr + k8 * 32 + lg * 8);
      f32x4 fb = *(const f32x4*)(xr + k8 * 32 + lg * 8 + 4);
      xf[tt][k8] = pack8(fa, fb);
    }
  }

  f32x4 acc2[2][16];                  // 32 tok x 256 h -> 128 regs (AGPR)
  #pragma unroll
  for (int tt = 0; tt < 2; ++tt)
    #pragma unroll
    for (int ht = 0; ht < 16; ++ht)
      acc2[tt][ht] = (f32x4){0.f, 0.f, 0.f, 0.f};

  const ushort* w1e = w1t + (size_t)e * F_ * H_;
  const ushort* w2e = w2t + (size_t)e * H_ * F_;
  uint4 w2rA[2], w2rB[2];             // split staging: 2+2 uint4 (trim live VGPRs)

  #define STAGE_W1(F0, NB)                                                       \
    { _Pragma("unroll")                                                          \
      for (int it = 0; it < 4; ++it){                                            \
        int row = wv + it * 8;                                                   \
        const ushort* gsrc = w1e + (size_t)((F0) + row) * H_                     \
                           + (((lane * 16) ^ ((row & 7) << 4)) >> 1);            \
        __builtin_amdgcn_global_load_lds((const u32_glb*)(uintptr_t)gsrc,        \
            (u32_lds*)(uintptr_t)(&sW1[(NB)][row * 512]), 16, 0, 0);             \
      } }
  // W2 elem (h,f): byte = h*64 + 8*((f>>2)^(h&7)) + (f&3)*2
  #define STAGE_W2_ISSUE(R, I0, F0)                                              \
    { _Pragma("unroll")                                                          \
      for (int i = 0; i < 2; ++i){                                               \
        int seg = ((I0) + i) * 512 + tid;                                        \
        R[i] = *(const uint4*)(w2e + (size_t)(seg >> 2) * F_ + (F0) + (seg & 3) * 8); \
      } }
  #define STAGE_W2_WRITE(R, I0, NB)                                              \
    { _Pragma("unroll")                                                          \
      for (int i = 0; i < 2; ++i){                                               \
        int seg = ((I0) + i) * 512 + tid;                                        \
        int h = seg >> 2, q = seg & 3, key = h & 7;                              \
        char* base = (char*)&sW2[(NB)][h * 32];                                  \
        *(uint2*)(base + 8 * ((2 * q) ^ key))     = make_uint2(R[i].x, R[i].y);  \
        *(uint2*)(base + 8 * ((2 * q + 1) ^ key)) = make_uint2(R[i].z, R[i].w);  \
      } }

  // ---- prologue: stage chunk 0 ----
  STAGE_W2_ISSUE(w2rA, 0, 0)
  STAGE_W2_ISSUE(w2rB, 2, 0)
  STAGE_W1(0, 0)
  STAGE_W2_WRITE(w2rA, 0, 0)
  STAGE_W2_WRITE(w2rB, 2, 0)
  asm volatile("s_waitcnt vmcnt(0)" ::: "memory");
  __syncthreads();

  for (int ch = 0; ch < 64; ++ch){
    const int f0  = ch * 32;
    const int cur = ch & 1, nxt = cur ^ 1;
    if (ch < 63){                      // prefetch next chunk (W1 DMA + first W2 pair)
      STAGE_W2_ISSUE(w2rA, 0, f0 + 32)
      STAGE_W1(f0 + 32, nxt)
    }

    // ---- GEMM1 partial (own K-half): afr reused across 2 token-tiles ----
    f32x4 a1c0[2], a1c1[2];            // [tt] for cf=0 (f 0..15) / cf=1 (f 16..31)
    a1c0[0] = (f32x4){0.f,0.f,0.f,0.f}; a1c0[1] = (f32x4){0.f,0.f,0.f,0.f};
    a1c1[0] = (f32x4){0.f,0.f,0.f,0.f}; a1c1[1] = (f32x4){0.f,0.f,0.f,0.f};
    #pragma unroll
    for (int cf = 0; cf < 2; ++cf){
      const int r  = cf * 16 + l15;
      const char* rbase = (const char*)&sW1[cur][r * 512];
      const int   sw    = (r & 7) << 4;
      #pragma unroll
      for (int k8 = 0; k8 < 8; ++k8){
        const int kk = kh * 8 + k8;
        bf16x8 afr = *(const bf16x8*)(rbase + (((kk * 64 + lg * 16) ^ sw)));
        if (cf == 0){
          a1c0[0] = __builtin_amdgcn_mfma_f32_16x16x32_bf16(afr, xf[0][k8], a1c0[0], 0, 0, 0);
          a1c0[1] = __builtin_amdgcn_mfma_f32_16x16x32_bf16(afr, xf[1][k8], a1c0[1], 0, 0, 0);
        } else {
          a1c1[0] = __builtin_amdgcn_mfma_f32_16x16x32_bf16(afr, xf[0][k8], a1c1[0], 0, 0, 0);
          a1c1[1] = __builtin_amdgcn_mfma_f32_16x16x32_bf16(afr, xf[1][k8], a1c1[1], 0, 0, 0);
        }
      }
    }

    // ---- exchange foreign-half partials (wave-uniform selects, no runtime reg-index)
    #pragma unroll
    for (int tt = 0; tt < 2; ++tt)
      sEx[tg][tt][kh][lane] = kh ? a1c0[tt] : a1c1[tt];   // my foreign half
    __syncthreads();                   // B1

    if (ch < 63) STAGE_W2_ISSUE(w2rB, 2, f0 + 32)         // 2nd W2 pair, hidden under GELU/GEMM2

    // ---- complete own f-half, bias + exact GELU, publish pa ----
    f32x4 bv = *(const f32x4*)(b1 + (size_t)e * F_ + f0 + kh * 16 + lg * 4);
    uint2 own[2];
    #pragma unroll
    for (int tt = 0; tt < 2; ++tt){
      f32x4 mine = kh ? a1c1[tt] : a1c0[tt];
      f32x4 tot  = mine + sEx[tg][tt][1 - kh][lane];
      f32x4 gv   = gelu4(tot + bv);    // lane: f = f0 + kh*16 + lg*4 + i, tok = tg*32+tt*16+l15
      own[tt].x = (uint)f2bf(gv[0]) | ((uint)f2bf(gv[1]) << 16);
      own[tt].y = (uint)f2bf(gv[2]) | ((uint)f2bf(gv[3]) << 16);
      sPa[tg][tt][kh][lane] = own[tt];
    }
    __syncthreads();                   // B2

    // ---- assemble full-K A-frags; GEMM2 on own 256-h half ----
    bf16x8 af2[2];
    #pragma unroll
    for (int tt = 0; tt < 2; ++tt){
      uint2 oth = sPa[tg][tt][1 - kh][lane];
      union { bf16x8 v; uint2 u[2]; } A;
      A.u[0] = kh ? oth : own[tt];     // elems 0-3 = f-half 0
      A.u[1] = kh ? own[tt] : oth;     // elems 4-7 = f-half 1
      af2[tt] = A.v;
    }
    #pragma unroll
    for (int ht = 0; ht < 16; ++ht){
      const int h   = kh * 256 + ht * 16 + l15;
      const int key = l15 & 7;         // == h&7
      const char* b = (const char*)&sW2[cur][h * 32];
      union { bf16x8 v; uint2 u[2]; } B;
      B.u[0] = *(const uint2*)(b + 8 * (lg ^ key));         // f = lg*4 + {0..3}
      B.u[1] = *(const uint2*)(b + 8 * ((lg + 4) ^ key));   // f = 16 + lg*4 + {0..3}
      acc2[0][ht] = __builtin_amdgcn_mfma_f32_16x16x32_bf16(af2[0], B.v, acc2[0][ht], 0, 0, 0);
      acc2[1][ht] = __builtin_amdgcn_mfma_f32_16x16x32_bf16(af2[1], B.v, acc2[1][ht], 0, 0, 0);
    }

    if (ch < 63){
      STAGE_W2_WRITE(w2rA, 0, nxt)
      STAGE_W2_WRITE(w2rB, 2, nxt)
    }
    asm volatile("s_waitcnt vmcnt(0)" ::: "memory");  // W1 DMA drained
    __syncthreads();                   // B3: buffers/exchange regions reusable
  }

  // ---- epilogue: tok = tg*32 + tt*16 + lg*4 + i, h = kh*256 + ht*16 + l15
  const size_t obase = (size_t)(g * E_ + e) * C_ + (c0 + tg * 32 + lg * 4);
  #pragma unroll
  for (int ht = 0; ht < 16; ++ht){
    const int h  = kh * 256 + ht * 16 + l15;
    const float bb = b2[(size_t)e * H_ + h];
    #pragma unroll
    for (int tt = 0; tt < 2; ++tt){
      #pragma unroll
      for (int i = 0; i < 4; ++i)
        out[(obase + tt * 16 + i) * H_ + h] = acc2[tt][ht][i] + bb;
    }
  }
  #undef STAGE_W1
  #undef STAGE_W2_ISSUE
  #undef STAGE_W2_WRITE
}

extern "C" void kernel_launch(void* const* d_in, const int* in_sizes, int n_in,
                              void* d_out, int out_size, void* d_ws, size_t ws_size,
                              hipStream_t stream){
  const float *x = nullptr, *b1 = nullptr, *b2 = nullptr;
  const float* w12[2] = {nullptr, nullptr}; int nw = 0;
  for (int i = 0; i < n_in; ++i){
    long s = (long)in_sizes[i];
    if      (s == (long)G_ * E_ * C_ * H_) x = (const float*)d_in[i];
    else if (s == (long)E_ * H_ * F_) { if (nw < 2) w12[nw++] = (const float*)d_in[i]; }
    else if (s == (long)E_ * F_) b1 = (const float*)d_in[i];
    else if (s == (long)E_ * H_) b2 = (const float*)d_in[i];
  }
  const float* w1 = w12[0];
  const float* w2 = w12[1];
  if (!x || !w1 || !w2 || !b1 || !b2){
    x  = (const float*)d_in[0];
    w1 = (const float*)d_in[1];
    b1 = (const float*)d_in[2];
    w2 = (const float*)d_in[3];
    b2 = (const float*)d_in[4];
  }

  ushort* w1t = (ushort*)d_ws;                       // [E][F][H] bf16
  ushort* w2t = w1t + (size_t)E_ * F_ * H_;          // [E][H][F] bf16

  transpose_cvt<<<dim3(F_ / 64, H_ / 64, E_), dim3(256), 0, stream>>>(w1, w1t, H_, F_);
  transpose_cvt<<<dim3(H_ / 64, F_ / 64, E_), dim3(256), 0, stream>>>(w2, w2t, F_, H_);

  ffn_fused5<<<dim3(E_ * 64), dim3(512), 0, stream>>>(x, b1, b2, w1t, w2t, (float*)d_out);
}